// Round 11
// baseline (939.975 us; speedup 1.0000x reference)
//
#include <hip/hip_runtime.h>

// GraphVAE on MI355X — all tensors float32, edge_index int32.
// pseudo == 0  =>  spline basis selects kernel 0 only  =>
//   spline_conv(x) = scatter_mean(x[src], dst) @ W[0] + x @ root + b
// Aggregate rows first (linearity), then small dense transforms.
// R5: grid-stride node loops — stage weights in LDS ONCE per block
//     (R4 staged 57KB per 4 nodes => 337us latency-bound decode).

#define IN 64
#define HID 64
#define LAT 32

// ---------------- scatter-add of x rows + degree ----------------
__global__ __launch_bounds__(256) void k_scatter_x(
    const float* __restrict__ x, const int* __restrict__ ei,
    float* __restrict__ S1, float* __restrict__ deg, int E) {
  int t = blockIdx.x * 256 + threadIdx.x;
  int e = t >> 6;
  if (e >= E) return;
  int lane = t & 63;
  int src = ei[e];
  int dst = ei[E + e];
  float v = x[(size_t)src * 64 + lane];
  atomicAdd(&S1[(size_t)dst * 64 + lane], v);
  if (lane == 0) atomicAdd(&deg[dst], 1.0f);
}

// ---------------- scatter-add of h rows ----------------
__global__ __launch_bounds__(256) void k_scatter_h(
    const float* __restrict__ h, const int* __restrict__ ei,
    float* __restrict__ S2, int E) {
  int t = blockIdx.x * 256 + threadIdx.x;
  int e = t >> 6;
  if (e >= E) return;
  int lane = t & 63;
  int src = ei[e];
  int dst = ei[E + e];
  float v = h[(size_t)src * 64 + lane];
  atomicAdd(&S2[(size_t)dst * 64 + lane], v);
}

// ---------------- conv1: h = relu((S1/deg) @ w1[0] + x @ root1 + b1) ----------------
__global__ __launch_bounds__(256) void k_conv1(
    const float* __restrict__ S1, const float* __restrict__ deg,
    const float* __restrict__ x,
    const float* __restrict__ w1, const float* __restrict__ root1,
    const float* __restrict__ b1,
    float* __restrict__ h, int N) {
  __shared__ float W[64][64];   // w1[0] : [IN][HID]
  __shared__ float R[64][64];   // root1 : [IN][HID]
  __shared__ float B[64];
  for (int i = threadIdx.x; i < 64 * 64; i += 256) {
    W[i >> 6][i & 63] = w1[i];       // first K-slice of w1
    R[i >> 6][i & 63] = root1[i];
  }
  if (threadIdx.x < 64) B[threadIdx.x] = b1[threadIdx.x];
  __syncthreads();

  int lane = threadIdx.x & 63;
  int stride = gridDim.x * 4;
  for (int n = blockIdx.x * 4 + (threadIdx.x >> 6); n < N; n += stride) {
    float invd = 1.0f / fmaxf(deg[n], 1.0f);
    float a  = S1[(size_t)n * 64 + lane] * invd;   // A1[n][lane]
    float xv = x[(size_t)n * 64 + lane];           // x[n][lane]

    float acc = B[lane];
    #pragma unroll
    for (int i = 0; i < 64; ++i) {
      float ai = __shfl(a, i);
      float xi = __shfl(xv, i);
      acc = fmaf(ai, W[i][lane], acc);
      acc = fmaf(xi, R[i][lane], acc);
    }
    h[(size_t)n * 64 + lane] = fmaxf(acc, 0.0f);
  }
}

// ---------------- decode: mu/logvar + reparam + fc1 + fc2 ----------------
// WA/RA packed: col j<32 -> mu weights, col j>=32 -> logvar weights.
__global__ __launch_bounds__(256) void k_decode(
    const float* __restrict__ S2, const float* __restrict__ deg,
    const float* __restrict__ h, const float* __restrict__ eps,
    const float* __restrict__ w_mu, const float* __restrict__ root_mu,
    const float* __restrict__ b_mu,
    const float* __restrict__ w_lv, const float* __restrict__ root_lv,
    const float* __restrict__ b_lv,
    const float* __restrict__ fc1_w, const float* __restrict__ fc1_b,
    const float* __restrict__ fc2_w, const float* __restrict__ fc2_b,
    float* __restrict__ out, int N) {
  __shared__ float WA[64][64];   // [i][j<32]=w_mu[0][i][j], [i][j>=32]=w_lv[0][i][j-32]
  __shared__ float RA[64][64];   // same packing of root_mu / root_lv
  __shared__ float F1[32][64];   // fc1_w [LAT][HID]
  __shared__ float F2[64][64];   // fc2_w [HID][IN]
  __shared__ float BA[64], B1[64], B2[64];

  for (int i = threadIdx.x; i < 64 * 32; i += 256) {
    int r = i >> 5, c = i & 31;
    WA[r][c]      = w_mu[i];      // first K-slice
    WA[r][c + 32] = w_lv[i];      // first K-slice
    RA[r][c]      = root_mu[i];
    RA[r][c + 32] = root_lv[i];
  }
  for (int i = threadIdx.x; i < 32 * 64; i += 256) F1[i >> 6][i & 63] = fc1_w[i];
  for (int i = threadIdx.x; i < 64 * 64; i += 256) F2[i >> 6][i & 63] = fc2_w[i];
  if (threadIdx.x < 32) {
    BA[threadIdx.x]      = b_mu[threadIdx.x];
    BA[threadIdx.x + 32] = b_lv[threadIdx.x];
  }
  if (threadIdx.x < 64) {
    B1[threadIdx.x] = fc1_b[threadIdx.x];
    B2[threadIdx.x] = fc2_b[threadIdx.x];
  }
  __syncthreads();

  int lane = threadIdx.x & 63;
  int j = lane & 31;
  size_t Ns = (size_t)N;
  int stride = gridDim.x * 4;
  for (int n = blockIdx.x * 4 + (threadIdx.x >> 6); n < N; n += stride) {
    float invd = 1.0f / fmaxf(deg[n], 1.0f);
    float a  = S2[(size_t)n * 64 + lane] * invd;   // A2[n][lane]
    float hv = h[(size_t)n * 64 + lane];           // h[n][lane]

    // Stage A: lanes 0..31 -> mu[j], lanes 32..63 -> logvar[j]
    float acc = BA[lane];
    #pragma unroll
    for (int i = 0; i < 64; ++i) {
      float ai = __shfl(a, i);
      float hi = __shfl(hv, i);
      acc = fmaf(ai, WA[i][lane], acc);
      acc = fmaf(hi, RA[i][lane], acc);
    }
    // out layout: recon[N*64] | mu[N*32] | logvar[N*32]
    if (lane < 32) out[Ns * 64 + (size_t)n * 32 + j] = acc;
    else           out[Ns * 96 + (size_t)n * 32 + j] = acc;

    // reparameterize: every lane computes z[j] (duplicated across halves)
    float mu_j = __shfl(acc, j);
    float lv_j = __shfl(acc, j + 32);
    float ev = eps[(size_t)n * 32 + j];
    float z = mu_j + ev * expf(0.5f * lv_j);

    // Stage B: hd[lane] = relu(sum_j z[j]*F1[j][lane] + B1[lane])
    float hd = B1[lane];
    #pragma unroll
    for (int jj = 0; jj < 32; ++jj) {
      float zj = __shfl(z, jj);
      hd = fmaf(zj, F1[jj][lane], hd);
    }
    hd = fmaxf(hd, 0.0f);

    // Stage C: recon[lane] = sum_k hd[k]*F2[k][lane] + B2[lane]
    float rc = B2[lane];
    #pragma unroll
    for (int k = 0; k < 64; ++k) {
      float hk = __shfl(hd, k);
      rc = fmaf(hk, F2[k][lane], rc);
    }
    out[(size_t)n * 64 + lane] = rc;
  }
}

extern "C" void kernel_launch(void* const* d_in, const int* in_sizes, int n_in,
                              void* d_out, int out_size, void* d_ws, size_t ws_size,
                              hipStream_t stream) {
  const float* x       = (const float*)d_in[0];
  const int*   ei      = (const int*)d_in[1];
  const float* eps     = (const float*)d_in[2];
  const float* w1      = (const float*)d_in[3];
  const float* root1   = (const float*)d_in[4];
  const float* b1      = (const float*)d_in[5];
  const float* w_mu    = (const float*)d_in[6];
  const float* root_mu = (const float*)d_in[7];
  const float* b_mu    = (const float*)d_in[8];
  const float* w_lv    = (const float*)d_in[9];
  const float* root_lv = (const float*)d_in[10];
  const float* b_lv    = (const float*)d_in[11];
  const float* fc1_w   = (const float*)d_in[12];
  const float* fc1_b   = (const float*)d_in[13];
  const float* fc2_w   = (const float*)d_in[14];
  const float* fc2_b   = (const float*)d_in[15];

  const int N = in_sizes[0] / 64;   // 50000
  const int E = in_sizes[1] / 2;    // 800000

  // workspace layout (f32): deg[N] | S1[N*64] (reused as S2) | h[N*64]
  float* deg = (float*)d_ws;
  float* S1  = deg + N;
  float* h   = S1 + (size_t)N * 64;
  float* S2  = S1;   // reuse after conv1 consumes S1

  int scatter_blocks = (E * 64 + 255) / 256;

  // zero deg + S1 (contiguous N*65 floats)
  hipMemsetAsync(deg, 0, sizeof(float) * (size_t)N * 65, stream);
  k_scatter_x<<<scatter_blocks, 256, 0, stream>>>(x, ei, S1, deg, E);
  // conv1: 32.25KB LDS -> 4 blocks/CU; 1024 blocks saturate 256 CUs
  k_conv1<<<1024, 256, 0, stream>>>(S1, deg, x, w1, root1, b1, h, N);
  // re-zero S1 to serve as S2
  hipMemsetAsync(S2, 0, sizeof(float) * (size_t)N * 64, stream);
  k_scatter_h<<<scatter_blocks, 256, 0, stream>>>(h, ei, S2, E);
  // decode: ~57KB LDS -> 2 blocks/CU; 512 blocks saturate
  k_decode<<<512, 256, 0, stream>>>(S2, deg, h, eps,
      w_mu, root_mu, b_mu, w_lv, root_lv, b_lv,
      fc1_w, fc1_b, fc2_w, fc2_b, (float*)d_out, N);
}

// Round 13
// 604.547 us; speedup vs baseline: 1.5548x; 1.5548x over previous
//
#include <hip/hip_runtime.h>

// GraphVAE on MI355X — all f32, edge_index int32.
// pseudo == 0  =>  spline selects kernel 0 only =>
//   spline_conv(x) = scatter_mean(x[src],dst) @ W[0] + x @ root + b
// R12: dense layers as LDS-tiled register-blocked GEMMs (4x4 acc/thread,
//      float4 LDS reads). R4/R11 wave-per-node shfl chains were latency-bound
//      (38K cyc/node). Weight LDS region (16KB) re-staged per phase to stay
//      under the 64KB static-LDS limit.

// ---------------- scatter-add of x rows + degree ----------------
__global__ __launch_bounds__(256) void k_scatter_x(
    const float* __restrict__ x, const int* __restrict__ ei,
    float* __restrict__ S1, float* __restrict__ deg, int E) {
  int t = blockIdx.x * 256 + threadIdx.x;
  int e = t >> 6;
  if (e >= E) return;
  int lane = t & 63;
  int src = ei[e];
  int dst = ei[E + e];
  float v = x[(size_t)src * 64 + lane];
  atomicAdd(&S1[(size_t)dst * 64 + lane], v);
  if (lane == 0) atomicAdd(&deg[dst], 1.0f);
}

// ---------------- scatter-add of h rows ----------------
__global__ __launch_bounds__(256) void k_scatter_h(
    const float* __restrict__ h, const int* __restrict__ ei,
    float* __restrict__ S2, int E) {
  int t = blockIdx.x * 256 + threadIdx.x;
  int e = t >> 6;
  if (e >= E) return;
  int lane = t & 63;
  int src = ei[e];
  int dst = ei[E + e];
  float v = h[(size_t)src * 64 + lane];
  atomicAdd(&S2[(size_t)dst * 64 + lane], v);
}

// 16-fma micro-tile step: rows use A float4 chunk, cols use W float4.
#define GEMM_STEP(ACC, AV, WROW, C0)                          \
  {                                                           \
    float4 w = *(const float4*)&WROW[C0];                     \
    _Pragma("unroll")                                         \
    for (int i_ = 0; i_ < 4; ++i_) {                          \
      float a_ = AV[i_];                                      \
      ACC[i_][0] = fmaf(a_, w.x, ACC[i_][0]);                 \
      ACC[i_][1] = fmaf(a_, w.y, ACC[i_][1]);                 \
      ACC[i_][2] = fmaf(a_, w.z, ACC[i_][2]);                 \
      ACC[i_][3] = fmaf(a_, w.w, ACC[i_][3]);                 \
    }                                                         \
  }

// ---------------- conv1: h = relu((S1/deg)@w1[0] + x@root1 + b1) ----------------
__global__ __launch_bounds__(256) void k_conv1(
    const float* __restrict__ S1, const float* __restrict__ deg,
    const float* __restrict__ x,
    const float* __restrict__ w1, const float* __restrict__ root1,
    const float* __restrict__ b1,
    float* __restrict__ h, int N) {
  __shared__ float A[64][132];   // cols 0..63: S1/deg ; 64..127: x
  __shared__ float Wt[64][64];   // staged twice: w1[0], then root1
  __shared__ float B[64];
  const int t = threadIdx.x;
  const int n0 = blockIdx.x * 64;

  for (int i = t; i < 4096; i += 256) Wt[i >> 6][i & 63] = w1[i];
  if (t < 64) B[t] = b1[t];
  {
    const int r = t >> 2, cc = (t & 3) * 16;
    const int n = n0 + r;
    if (n < N) {
      const float invd = 1.0f / fmaxf(deg[n], 1.0f);
      const float* sp = S1 + (size_t)n * 64 + cc;
      const float* xp = x + (size_t)n * 64 + cc;
      #pragma unroll
      for (int j = 0; j < 16; ++j) {
        A[r][cc + j]      = sp[j] * invd;
        A[r][64 + cc + j] = xp[j];
      }
    } else {
      #pragma unroll
      for (int j = 0; j < 16; ++j) { A[r][cc + j] = 0.f; A[r][64 + cc + j] = 0.f; }
    }
  }
  __syncthreads();

  const int r0 = (t >> 4) * 4, c0 = (t & 15) * 4;
  float acc[4][4];
  #pragma unroll
  for (int i = 0; i < 4; ++i) {
    acc[i][0] = B[c0]; acc[i][1] = B[c0 + 1]; acc[i][2] = B[c0 + 2]; acc[i][3] = B[c0 + 3];
  }

  // K-half 1: A cols 0..63 x w1[0]
  for (int k = 0; k < 64; k += 4) {
    float4 a4[4]; float av[4];
    #pragma unroll
    for (int i = 0; i < 4; ++i) a4[i] = *(const float4*)&A[r0 + i][k];
    #pragma unroll
    for (int kk = 0; kk < 4; ++kk) {
      #pragma unroll
      for (int i = 0; i < 4; ++i)
        av[i] = (kk == 0) ? a4[i].x : (kk == 1) ? a4[i].y : (kk == 2) ? a4[i].z : a4[i].w;
      GEMM_STEP(acc, av, Wt[k + kk], c0)
    }
  }
  __syncthreads();
  for (int i = t; i < 4096; i += 256) Wt[i >> 6][i & 63] = root1[i];
  __syncthreads();
  // K-half 2: A cols 64..127 x root1
  for (int k = 0; k < 64; k += 4) {
    float4 a4[4]; float av[4];
    #pragma unroll
    for (int i = 0; i < 4; ++i) a4[i] = *(const float4*)&A[r0 + i][64 + k];
    #pragma unroll
    for (int kk = 0; kk < 4; ++kk) {
      #pragma unroll
      for (int i = 0; i < 4; ++i)
        av[i] = (kk == 0) ? a4[i].x : (kk == 1) ? a4[i].y : (kk == 2) ? a4[i].z : a4[i].w;
      GEMM_STEP(acc, av, Wt[k + kk], c0)
    }
  }

  #pragma unroll
  for (int i = 0; i < 4; ++i) {
    const int n = n0 + r0 + i;
    if (n < N) {
      float4 o;
      o.x = fmaxf(acc[i][0], 0.f); o.y = fmaxf(acc[i][1], 0.f);
      o.z = fmaxf(acc[i][2], 0.f); o.w = fmaxf(acc[i][3], 0.f);
      *(float4*)&h[(size_t)n * 64 + c0] = o;
    }
  }
}

// ---------------- decode: mu/lv (K=128) + reparam + fc1 (K=32) + fc2 (K=64) ----------------
// LDS A[64][132]: phase1 cols 0..63 = S2/deg, 64..127 = h.
// After phase1: cols 0..63 reused as hd, cols 64..95 reused as z.
// Wt[64][64] staged 4x: WA(mu|lv packed), RA, F1(rows 0..31), F2.
__global__ __launch_bounds__(256) void k_decode(
    const float* __restrict__ S2, const float* __restrict__ deg,
    const float* __restrict__ h, const float* __restrict__ eps,
    const float* __restrict__ w_mu, const float* __restrict__ root_mu,
    const float* __restrict__ b_mu,
    const float* __restrict__ w_lv, const float* __restrict__ root_lv,
    const float* __restrict__ b_lv,
    const float* __restrict__ fc1_w, const float* __restrict__ fc1_b,
    const float* __restrict__ fc2_w, const float* __restrict__ fc2_b,
    float* __restrict__ out, int N) {
  __shared__ float A[64][132];
  __shared__ float Wt[64][64];
  __shared__ float BA[64], B1s[64], B2s[64];
  const int t = threadIdx.x;
  const int n0 = blockIdx.x * 64;
  const size_t Ns = (size_t)N;

  // stage WA: [i>>5][ (i&31) | +32 ] = w_mu | w_lv  (kernel-0 slices)
  for (int i = t; i < 2048; i += 256) {
    int r = i >> 5, c = i & 31;
    Wt[r][c]      = w_mu[i];
    Wt[r][c + 32] = w_lv[i];
  }
  if (t < 32) { BA[t] = b_mu[t]; BA[t + 32] = b_lv[t]; }
  if (t < 64) { B1s[t] = fc1_b[t]; B2s[t] = fc2_b[t]; }
  {
    const int r = t >> 2, cc = (t & 3) * 16;
    const int n = n0 + r;
    if (n < N) {
      const float invd = 1.0f / fmaxf(deg[n], 1.0f);
      const float* sp = S2 + (size_t)n * 64 + cc;
      const float* hp = h + (size_t)n * 64 + cc;
      #pragma unroll
      for (int j = 0; j < 16; ++j) {
        A[r][cc + j]      = sp[j] * invd;
        A[r][64 + cc + j] = hp[j];
      }
    } else {
      #pragma unroll
      for (int j = 0; j < 16; ++j) { A[r][cc + j] = 0.f; A[r][64 + cc + j] = 0.f; }
    }
  }
  __syncthreads();

  const int r0 = (t >> 4) * 4, c0 = (t & 15) * 4;
  const int lane = t & 63;
  const int tc = t & 15;
  float acc[4][4];
  #pragma unroll
  for (int i = 0; i < 4; ++i) {
    acc[i][0] = BA[c0]; acc[i][1] = BA[c0 + 1]; acc[i][2] = BA[c0 + 2]; acc[i][3] = BA[c0 + 3];
  }

  // phase 1a: agg part (A cols 0..63) x WA
  for (int k = 0; k < 64; k += 4) {
    float4 a4[4]; float av[4];
    #pragma unroll
    for (int i = 0; i < 4; ++i) a4[i] = *(const float4*)&A[r0 + i][k];
    #pragma unroll
    for (int kk = 0; kk < 4; ++kk) {
      #pragma unroll
      for (int i = 0; i < 4; ++i)
        av[i] = (kk == 0) ? a4[i].x : (kk == 1) ? a4[i].y : (kk == 2) ? a4[i].z : a4[i].w;
      GEMM_STEP(acc, av, Wt[k + kk], c0)
    }
  }
  __syncthreads();
  // stage RA
  for (int i = t; i < 2048; i += 256) {
    int r = i >> 5, c = i & 31;
    Wt[r][c]      = root_mu[i];
    Wt[r][c + 32] = root_lv[i];
  }
  __syncthreads();
  // phase 1b: h part (A cols 64..127) x RA
  for (int k = 0; k < 64; k += 4) {
    float4 a4[4]; float av[4];
    #pragma unroll
    for (int i = 0; i < 4; ++i) a4[i] = *(const float4*)&A[r0 + i][64 + k];
    #pragma unroll
    for (int kk = 0; kk < 4; ++kk) {
      #pragma unroll
      for (int i = 0; i < 4; ++i)
        av[i] = (kk == 0) ? a4[i].x : (kk == 1) ? a4[i].y : (kk == 2) ? a4[i].z : a4[i].w;
      GEMM_STEP(acc, av, Wt[k + kk], c0)
    }
  }
  __syncthreads();   // all phase-1 reads of A/Wt done

  // epilogue: write mu/lv; z -> A cols 64..95; stage F1 -> Wt rows 0..31
  #pragma unroll
  for (int i = 0; i < 4; ++i) {
    const int n = n0 + r0 + i;
    if (n < N) {
      float4 o = {acc[i][0], acc[i][1], acc[i][2], acc[i][3]};
      if (tc < 8) *(float4*)&out[Ns * 64 + (size_t)n * 32 + c0] = o;
      else        *(float4*)&out[Ns * 96 + (size_t)n * 32 + (c0 - 32)] = o;
    }
  }
  #pragma unroll
  for (int i = 0; i < 4; ++i) {
    #pragma unroll
    for (int j = 0; j < 4; ++j) {
      float lvv = __shfl(acc[i][j], lane + 8);   // partner lane holds lv for same col
      if (tc < 8) {
        const int n = n0 + r0 + i;
        float ev = (n < N) ? eps[(size_t)n * 32 + c0 + j] : 0.f;
        A[r0 + i][64 + c0 + j] = acc[i][j] + ev * expf(0.5f * lvv);  // z
      }
    }
  }
  for (int i = t; i < 2048; i += 256) Wt[i >> 6][i & 63] = fc1_w[i];  // F1: rows 0..31
  __syncthreads();

  // phase 2: hd = relu(z @ F1 + b1) -> A cols 0..63
  float acc2[4][4];
  #pragma unroll
  for (int i = 0; i < 4; ++i) {
    acc2[i][0] = B1s[c0]; acc2[i][1] = B1s[c0 + 1]; acc2[i][2] = B1s[c0 + 2]; acc2[i][3] = B1s[c0 + 3];
  }
  for (int k = 0; k < 32; k += 4) {
    float4 a4[4]; float av[4];
    #pragma unroll
    for (int i = 0; i < 4; ++i) a4[i] = *(const float4*)&A[r0 + i][64 + k];  // z
    #pragma unroll
    for (int kk = 0; kk < 4; ++kk) {
      #pragma unroll
      for (int i = 0; i < 4; ++i)
        av[i] = (kk == 0) ? a4[i].x : (kk == 1) ? a4[i].y : (kk == 2) ? a4[i].z : a4[i].w;
      GEMM_STEP(acc2, av, Wt[k + kk], c0)
    }
  }
  #pragma unroll
  for (int i = 0; i < 4; ++i) {
    #pragma unroll
    for (int j = 0; j < 4; ++j) A[r0 + i][c0 + j] = fmaxf(acc2[i][j], 0.f);  // hd
  }
  __syncthreads();   // hd visible; all F1 reads done
  for (int i = t; i < 4096; i += 256) Wt[i >> 6][i & 63] = fc2_w[i];  // F2
  __syncthreads();

  // phase 3: recon = hd @ F2 + b2
  float acc3[4][4];
  #pragma unroll
  for (int i = 0; i < 4; ++i) {
    acc3[i][0] = B2s[c0]; acc3[i][1] = B2s[c0 + 1]; acc3[i][2] = B2s[c0 + 2]; acc3[i][3] = B2s[c0 + 3];
  }
  for (int k = 0; k < 64; k += 4) {
    float4 a4[4]; float av[4];
    #pragma unroll
    for (int i = 0; i < 4; ++i) a4[i] = *(const float4*)&A[r0 + i][k];  // hd
    #pragma unroll
    for (int kk = 0; kk < 4; ++kk) {
      #pragma unroll
      for (int i = 0; i < 4; ++i)
        av[i] = (kk == 0) ? a4[i].x : (kk == 1) ? a4[i].y : (kk == 2) ? a4[i].z : a4[i].w;
      GEMM_STEP(acc3, av, Wt[k + kk], c0)
    }
  }
  #pragma unroll
  for (int i = 0; i < 4; ++i) {
    const int n = n0 + r0 + i;
    if (n < N) {
      float4 o = {acc3[i][0], acc3[i][1], acc3[i][2], acc3[i][3]};
      *(float4*)&out[(size_t)n * 64 + c0] = o;
    }
  }
}

extern "C" void kernel_launch(void* const* d_in, const int* in_sizes, int n_in,
                              void* d_out, int out_size, void* d_ws, size_t ws_size,
                              hipStream_t stream) {
  const float* x       = (const float*)d_in[0];
  const int*   ei      = (const int*)d_in[1];
  const float* eps     = (const float*)d_in[2];
  const float* w1      = (const float*)d_in[3];
  const float* root1   = (const float*)d_in[4];
  const float* b1      = (const float*)d_in[5];
  const float* w_mu    = (const float*)d_in[6];
  const float* root_mu = (const float*)d_in[7];
  const float* b_mu    = (const float*)d_in[8];
  const float* w_lv    = (const float*)d_in[9];
  const float* root_lv = (const float*)d_in[10];
  const float* b_lv    = (const float*)d_in[11];
  const float* fc1_w   = (const float*)d_in[12];
  const float* fc1_b   = (const float*)d_in[13];
  const float* fc2_w   = (const float*)d_in[14];
  const float* fc2_b   = (const float*)d_in[15];

  const int N = in_sizes[0] / 64;   // 50000
  const int E = in_sizes[1] / 2;    // 800000

  // workspace (f32): deg[N] | S1[N*64] (reused as S2) | h[N*64]
  float* deg = (float*)d_ws;
  float* S1  = deg + N;
  float* h   = S1 + (size_t)N * 64;
  float* S2  = S1;

  const int scatter_blocks = (E * 64 + 255) / 256;
  const int dense_blocks   = (N + 63) / 64;

  hipMemsetAsync(deg, 0, sizeof(float) * (size_t)N * 65, stream);
  k_scatter_x<<<scatter_blocks, 256, 0, stream>>>(x, ei, S1, deg, E);
  k_conv1<<<dense_blocks, 256, 0, stream>>>(S1, deg, x, w1, root1, b1, h, N);
  hipMemsetAsync(S2, 0, sizeof(float) * (size_t)N * 64, stream);
  k_scatter_h<<<scatter_blocks, 256, 0, stream>>>(h, ei, S2, E);
  k_decode<<<dense_blocks, 256, 0, stream>>>(S2, deg, h, eps,
      w_mu, root_mu, b_mu, w_lv, root_lv, b_lv,
      fc1_w, fc1_b, fc2_w, fc2_b, (float*)d_out, N);
}

// Round 15
// 375.866 us; speedup vs baseline: 2.5008x; 1.6084x over previous
//
#include <hip/hip_runtime.h>

// GraphVAE on MI355X — all f32, edge_index int32.
// pseudo == 0 => spline kernel 0 only =>
//   spline_conv(x) = scatter_mean(x[src],dst) @ W[0] + x @ root + b
// R12: dense layers = LDS-tiled register-blocked GEMMs (kept verbatim).
// R14: aggregation via CSR-gather (hist -> scan -> place -> gather).
//      R13 counters: scatter_x 211us, 225MB atomic WRITE stream = the bound.
//      Gather removes all f32 atomics; deg comes from row_ptr.

// ================= CSR build =================
__global__ __launch_bounds__(256) void k_hist(
    const int* __restrict__ ei, int* __restrict__ cnt, int E) {
  int e = blockIdx.x * 256 + threadIdx.x;
  if (e < E) atomicAdd(&cnt[ei[E + e]], 1);
}

// inclusive Hillis-Steele block scan over 256 ints in LDS
#define BLOCK_SCAN(sarr, tid)                          \
  for (int off_ = 1; off_ < 256; off_ <<= 1) {         \
    __syncthreads();                                   \
    int tmp_ = (tid >= off_) ? sarr[tid - off_] : 0;   \
    __syncthreads();                                   \
    sarr[tid] += tmp_;                                 \
  }                                                    \
  __syncthreads();

__global__ __launch_bounds__(256) void k_scan1(
    const int* __restrict__ cnt, int* __restrict__ partials, int N) {
  __shared__ int s[256];
  int t = threadIdx.x, idx = blockIdx.x * 256 + t;
  int v = (idx < N) ? cnt[idx] : 0;
  s[t] = v;
  BLOCK_SCAN(s, t)
  if (t == 255) partials[blockIdx.x] = s[255];
}

__global__ __launch_bounds__(256) void k_scan2(
    int* __restrict__ partials, int B) {
  __shared__ int s[256];
  int t = threadIdx.x;
  int v = (t < B) ? partials[t] : 0;
  s[t] = v;
  BLOCK_SCAN(s, t)
  if (t < B) partials[t] = s[t] - v;   // exclusive
}

__global__ __launch_bounds__(256) void k_scan3(
    const int* __restrict__ cnt, const int* __restrict__ partials,
    int* __restrict__ row_ptr, int N, int E) {
  __shared__ int s[256];
  int t = threadIdx.x, idx = blockIdx.x * 256 + t;
  int v = (idx < N) ? cnt[idx] : 0;
  s[t] = v;
  BLOCK_SCAN(s, t)
  if (idx < N) row_ptr[idx] = partials[blockIdx.x] + s[t] - v;  // exclusive global
  if (blockIdx.x == 0 && t == 0) row_ptr[N] = E;
}

__global__ __launch_bounds__(256) void k_place(
    const int* __restrict__ ei, const int* __restrict__ row_ptr,
    int* __restrict__ cursor, int* __restrict__ col_idx, int E) {
  int e = blockIdx.x * 256 + threadIdx.x;
  if (e >= E) return;
  int dst = ei[E + e];
  int slot = atomicAdd(&cursor[dst], 1);
  col_idx[row_ptr[dst] + slot] = ei[e];   // src
}

// ================= gather-sum of neighbor rows =================
__global__ __launch_bounds__(256) void k_gather(
    const float* __restrict__ src, const int* __restrict__ row_ptr,
    const int* __restrict__ col_idx, float* __restrict__ S, int N) {
  int n = blockIdx.x * 4 + (threadIdx.x >> 6);
  if (n >= N) return;
  int lane = threadIdx.x & 63;
  int j = row_ptr[n], end = row_ptr[n + 1];
  float acc = 0.f;
  for (; j + 4 <= end; j += 4) {
    int s0 = col_idx[j], s1 = col_idx[j + 1], s2 = col_idx[j + 2], s3 = col_idx[j + 3];
    float v0 = src[(size_t)s0 * 64 + lane];
    float v1 = src[(size_t)s1 * 64 + lane];
    float v2 = src[(size_t)s2 * 64 + lane];
    float v3 = src[(size_t)s3 * 64 + lane];
    acc += (v0 + v1) + (v2 + v3);
  }
  for (; j < end; ++j) acc += src[(size_t)col_idx[j] * 64 + lane];
  S[(size_t)n * 64 + lane] = acc;
}

// 16-fma micro-tile step: rows use A float4 chunk, cols use W float4.
#define GEMM_STEP(ACC, AV, WROW, C0)                          \
  {                                                           \
    float4 w = *(const float4*)&WROW[C0];                     \
    _Pragma("unroll")                                         \
    for (int i_ = 0; i_ < 4; ++i_) {                          \
      float a_ = AV[i_];                                      \
      ACC[i_][0] = fmaf(a_, w.x, ACC[i_][0]);                 \
      ACC[i_][1] = fmaf(a_, w.y, ACC[i_][1]);                 \
      ACC[i_][2] = fmaf(a_, w.z, ACC[i_][2]);                 \
      ACC[i_][3] = fmaf(a_, w.w, ACC[i_][3]);                 \
    }                                                         \
  }

// ---------------- conv1: h = relu((S1/deg)@w1[0] + x@root1 + b1) ----------------
__global__ __launch_bounds__(256) void k_conv1(
    const float* __restrict__ S1, const int* __restrict__ row_ptr,
    const float* __restrict__ x,
    const float* __restrict__ w1, const float* __restrict__ root1,
    const float* __restrict__ b1,
    float* __restrict__ h, int N) {
  __shared__ float A[64][132];   // cols 0..63: S1/deg ; 64..127: x
  __shared__ float Wt[64][64];   // staged twice: w1[0], then root1
  __shared__ float B[64];
  const int t = threadIdx.x;
  const int n0 = blockIdx.x * 64;

  for (int i = t; i < 4096; i += 256) Wt[i >> 6][i & 63] = w1[i];
  if (t < 64) B[t] = b1[t];
  {
    const int r = t >> 2, cc = (t & 3) * 16;
    const int n = n0 + r;
    if (n < N) {
      const float dg = (float)(row_ptr[n + 1] - row_ptr[n]);
      const float invd = 1.0f / fmaxf(dg, 1.0f);
      const float* sp = S1 + (size_t)n * 64 + cc;
      const float* xp = x + (size_t)n * 64 + cc;
      #pragma unroll
      for (int j = 0; j < 16; ++j) {
        A[r][cc + j]      = sp[j] * invd;
        A[r][64 + cc + j] = xp[j];
      }
    } else {
      #pragma unroll
      for (int j = 0; j < 16; ++j) { A[r][cc + j] = 0.f; A[r][64 + cc + j] = 0.f; }
    }
  }
  __syncthreads();

  const int r0 = (t >> 4) * 4, c0 = (t & 15) * 4;
  float acc[4][4];
  #pragma unroll
  for (int i = 0; i < 4; ++i) {
    acc[i][0] = B[c0]; acc[i][1] = B[c0 + 1]; acc[i][2] = B[c0 + 2]; acc[i][3] = B[c0 + 3];
  }

  // K-half 1: A cols 0..63 x w1[0]
  for (int k = 0; k < 64; k += 4) {
    float4 a4[4]; float av[4];
    #pragma unroll
    for (int i = 0; i < 4; ++i) a4[i] = *(const float4*)&A[r0 + i][k];
    #pragma unroll
    for (int kk = 0; kk < 4; ++kk) {
      #pragma unroll
      for (int i = 0; i < 4; ++i)
        av[i] = (kk == 0) ? a4[i].x : (kk == 1) ? a4[i].y : (kk == 2) ? a4[i].z : a4[i].w;
      GEMM_STEP(acc, av, Wt[k + kk], c0)
    }
  }
  __syncthreads();
  for (int i = t; i < 4096; i += 256) Wt[i >> 6][i & 63] = root1[i];
  __syncthreads();
  // K-half 2: A cols 64..127 x root1
  for (int k = 0; k < 64; k += 4) {
    float4 a4[4]; float av[4];
    #pragma unroll
    for (int i = 0; i < 4; ++i) a4[i] = *(const float4*)&A[r0 + i][64 + k];
    #pragma unroll
    for (int kk = 0; kk < 4; ++kk) {
      #pragma unroll
      for (int i = 0; i < 4; ++i)
        av[i] = (kk == 0) ? a4[i].x : (kk == 1) ? a4[i].y : (kk == 2) ? a4[i].z : a4[i].w;
      GEMM_STEP(acc, av, Wt[k + kk], c0)
    }
  }

  #pragma unroll
  for (int i = 0; i < 4; ++i) {
    const int n = n0 + r0 + i;
    if (n < N) {
      float4 o;
      o.x = fmaxf(acc[i][0], 0.f); o.y = fmaxf(acc[i][1], 0.f);
      o.z = fmaxf(acc[i][2], 0.f); o.w = fmaxf(acc[i][3], 0.f);
      *(float4*)&h[(size_t)n * 64 + c0] = o;
    }
  }
}

// ---------------- decode: mu/lv (K=128) + reparam + fc1 (K=32) + fc2 (K=64) ----------------
// LDS A[64][132]: phase1 cols 0..63 = S2/deg, 64..127 = h.
// After phase1: cols 0..63 reused as hd, cols 64..95 reused as z.
// Wt[64][64] staged 4x: WA(mu|lv packed), RA, F1(rows 0..31), F2.
__global__ __launch_bounds__(256) void k_decode(
    const float* __restrict__ S2, const int* __restrict__ row_ptr,
    const float* __restrict__ h, const float* __restrict__ eps,
    const float* __restrict__ w_mu, const float* __restrict__ root_mu,
    const float* __restrict__ b_mu,
    const float* __restrict__ w_lv, const float* __restrict__ root_lv,
    const float* __restrict__ b_lv,
    const float* __restrict__ fc1_w, const float* __restrict__ fc1_b,
    const float* __restrict__ fc2_w, const float* __restrict__ fc2_b,
    float* __restrict__ out, int N) {
  __shared__ float A[64][132];
  __shared__ float Wt[64][64];
  __shared__ float BA[64], B1s[64], B2s[64];
  const int t = threadIdx.x;
  const int n0 = blockIdx.x * 64;
  const size_t Ns = (size_t)N;

  // stage WA: col j<32 = w_mu, col j>=32 = w_lv (kernel-0 slices)
  for (int i = t; i < 2048; i += 256) {
    int r = i >> 5, c = i & 31;
    Wt[r][c]      = w_mu[i];
    Wt[r][c + 32] = w_lv[i];
  }
  if (t < 32) { BA[t] = b_mu[t]; BA[t + 32] = b_lv[t]; }
  if (t < 64) { B1s[t] = fc1_b[t]; B2s[t] = fc2_b[t]; }
  {
    const int r = t >> 2, cc = (t & 3) * 16;
    const int n = n0 + r;
    if (n < N) {
      const float dg = (float)(row_ptr[n + 1] - row_ptr[n]);
      const float invd = 1.0f / fmaxf(dg, 1.0f);
      const float* sp = S2 + (size_t)n * 64 + cc;
      const float* hp = h + (size_t)n * 64 + cc;
      #pragma unroll
      for (int j = 0; j < 16; ++j) {
        A[r][cc + j]      = sp[j] * invd;
        A[r][64 + cc + j] = hp[j];
      }
    } else {
      #pragma unroll
      for (int j = 0; j < 16; ++j) { A[r][cc + j] = 0.f; A[r][64 + cc + j] = 0.f; }
    }
  }
  __syncthreads();

  const int r0 = (t >> 4) * 4, c0 = (t & 15) * 4;
  const int lane = t & 63;
  const int tc = t & 15;
  float acc[4][4];
  #pragma unroll
  for (int i = 0; i < 4; ++i) {
    acc[i][0] = BA[c0]; acc[i][1] = BA[c0 + 1]; acc[i][2] = BA[c0 + 2]; acc[i][3] = BA[c0 + 3];
  }

  // phase 1a: agg part (A cols 0..63) x WA
  for (int k = 0; k < 64; k += 4) {
    float4 a4[4]; float av[4];
    #pragma unroll
    for (int i = 0; i < 4; ++i) a4[i] = *(const float4*)&A[r0 + i][k];
    #pragma unroll
    for (int kk = 0; kk < 4; ++kk) {
      #pragma unroll
      for (int i = 0; i < 4; ++i)
        av[i] = (kk == 0) ? a4[i].x : (kk == 1) ? a4[i].y : (kk == 2) ? a4[i].z : a4[i].w;
      GEMM_STEP(acc, av, Wt[k + kk], c0)
    }
  }
  __syncthreads();
  // stage RA
  for (int i = t; i < 2048; i += 256) {
    int r = i >> 5, c = i & 31;
    Wt[r][c]      = root_mu[i];
    Wt[r][c + 32] = root_lv[i];
  }
  __syncthreads();
  // phase 1b: h part (A cols 64..127) x RA
  for (int k = 0; k < 64; k += 4) {
    float4 a4[4]; float av[4];
    #pragma unroll
    for (int i = 0; i < 4; ++i) a4[i] = *(const float4*)&A[r0 + i][64 + k];
    #pragma unroll
    for (int kk = 0; kk < 4; ++kk) {
      #pragma unroll
      for (int i = 0; i < 4; ++i)
        av[i] = (kk == 0) ? a4[i].x : (kk == 1) ? a4[i].y : (kk == 2) ? a4[i].z : a4[i].w;
      GEMM_STEP(acc, av, Wt[k + kk], c0)
    }
  }
  __syncthreads();   // all phase-1 reads of A/Wt done

  // epilogue: write mu/lv; z -> A cols 64..95; stage F1 -> Wt rows 0..31
  #pragma unroll
  for (int i = 0; i < 4; ++i) {
    const int n = n0 + r0 + i;
    if (n < N) {
      float4 o = {acc[i][0], acc[i][1], acc[i][2], acc[i][3]};
      if (tc < 8) *(float4*)&out[Ns * 64 + (size_t)n * 32 + c0] = o;
      else        *(float4*)&out[Ns * 96 + (size_t)n * 32 + (c0 - 32)] = o;
    }
  }
  #pragma unroll
  for (int i = 0; i < 4; ++i) {
    #pragma unroll
    for (int j = 0; j < 4; ++j) {
      float lvv = __shfl(acc[i][j], lane + 8);   // partner lane holds lv for same col
      if (tc < 8) {
        const int n = n0 + r0 + i;
        float ev = (n < N) ? eps[(size_t)n * 32 + c0 + j] : 0.f;
        A[r0 + i][64 + c0 + j] = acc[i][j] + ev * expf(0.5f * lvv);  // z
      }
    }
  }
  for (int i = t; i < 2048; i += 256) Wt[i >> 6][i & 63] = fc1_w[i];  // F1: rows 0..31
  __syncthreads();

  // phase 2: hd = relu(z @ F1 + b1) -> A cols 0..63
  float acc2[4][4];
  #pragma unroll
  for (int i = 0; i < 4; ++i) {
    acc2[i][0] = B1s[c0]; acc2[i][1] = B1s[c0 + 1]; acc2[i][2] = B1s[c0 + 2]; acc2[i][3] = B1s[c0 + 3];
  }
  for (int k = 0; k < 32; k += 4) {
    float4 a4[4]; float av[4];
    #pragma unroll
    for (int i = 0; i < 4; ++i) a4[i] = *(const float4*)&A[r0 + i][64 + k];  // z
    #pragma unroll
    for (int kk = 0; kk < 4; ++kk) {
      #pragma unroll
      for (int i = 0; i < 4; ++i)
        av[i] = (kk == 0) ? a4[i].x : (kk == 1) ? a4[i].y : (kk == 2) ? a4[i].z : a4[i].w;
      GEMM_STEP(acc2, av, Wt[k + kk], c0)
    }
  }
  #pragma unroll
  for (int i = 0; i < 4; ++i) {
    #pragma unroll
    for (int j = 0; j < 4; ++j) A[r0 + i][c0 + j] = fmaxf(acc2[i][j], 0.f);  // hd
  }
  __syncthreads();   // hd visible; all F1 reads done
  for (int i = t; i < 4096; i += 256) Wt[i >> 6][i & 63] = fc2_w[i];  // F2
  __syncthreads();

  // phase 3: recon = hd @ F2 + b2
  float acc3[4][4];
  #pragma unroll
  for (int i = 0; i < 4; ++i) {
    acc3[i][0] = B2s[c0]; acc3[i][1] = B2s[c0 + 1]; acc3[i][2] = B2s[c0 + 2]; acc3[i][3] = B2s[c0 + 3];
  }
  for (int k = 0; k < 64; k += 4) {
    float4 a4[4]; float av[4];
    #pragma unroll
    for (int i = 0; i < 4; ++i) a4[i] = *(const float4*)&A[r0 + i][k];  // hd
    #pragma unroll
    for (int kk = 0; kk < 4; ++kk) {
      #pragma unroll
      for (int i = 0; i < 4; ++i)
        av[i] = (kk == 0) ? a4[i].x : (kk == 1) ? a4[i].y : (kk == 2) ? a4[i].z : a4[i].w;
      GEMM_STEP(acc3, av, Wt[k + kk], c0)
    }
  }
  #pragma unroll
  for (int i = 0; i < 4; ++i) {
    const int n = n0 + r0 + i;
    if (n < N) {
      float4 o = {acc3[i][0], acc3[i][1], acc3[i][2], acc3[i][3]};
      *(float4*)&out[(size_t)n * 64 + c0] = o;
    }
  }
}

extern "C" void kernel_launch(void* const* d_in, const int* in_sizes, int n_in,
                              void* d_out, int out_size, void* d_ws, size_t ws_size,
                              hipStream_t stream) {
  const float* x       = (const float*)d_in[0];
  const int*   ei      = (const int*)d_in[1];
  const float* eps     = (const float*)d_in[2];
  const float* w1      = (const float*)d_in[3];
  const float* root1   = (const float*)d_in[4];
  const float* b1      = (const float*)d_in[5];
  const float* w_mu    = (const float*)d_in[6];
  const float* root_mu = (const float*)d_in[7];
  const float* b_mu    = (const float*)d_in[8];
  const float* w_lv    = (const float*)d_in[9];
  const float* root_lv = (const float*)d_in[10];
  const float* b_lv    = (const float*)d_in[11];
  const float* fc1_w   = (const float*)d_in[12];
  const float* fc1_b   = (const float*)d_in[13];
  const float* fc2_w   = (const float*)d_in[14];
  const float* fc2_b   = (const float*)d_in[15];

  const int N = in_sizes[0] / 64;   // 50000
  const int E = in_sizes[1] / 2;    // 800000

  // ---- workspace layout ----
  // ints: cnt[N] | cursor[N] | row_ptr[Np] | partials[256] | col_idx[E]
  // floats (16B-aligned): S1[N*64] (reused as S2) | h[N*64]
  const int Np = ((N + 1 + 3) / 4) * 4;           // row_ptr padded
  int* cnt      = (int*)d_ws;
  int* cursor   = cnt + N;
  int* row_ptr  = cursor + N;
  int* partials = row_ptr + Np;
  int* col_idx  = partials + 256;
  float* S1 = (float*)(col_idx + E);
  float* h  = S1 + (size_t)N * 64;

  const int eb = (E + 255) / 256;                 // edge-parallel blocks
  const int sb = (N + 255) / 256;                 // scan blocks (<=256 req.)
  const int gb = (N + 3) / 4;                     // gather blocks
  const int db = (N + 63) / 64;                   // dense blocks

  // CSR build
  hipMemsetAsync(cnt, 0, sizeof(int) * (size_t)N * 2, stream);  // cnt + cursor
  k_hist <<<eb, 256, 0, stream>>>(ei, cnt, E);
  k_scan1<<<sb, 256, 0, stream>>>(cnt, partials, N);
  k_scan2<<<1,  256, 0, stream>>>(partials, sb);
  k_scan3<<<sb, 256, 0, stream>>>(cnt, partials, row_ptr, N, E);
  k_place<<<eb, 256, 0, stream>>>(ei, row_ptr, cursor, col_idx, E);

  // layer 1
  k_gather<<<gb, 256, 0, stream>>>(x, row_ptr, col_idx, S1, N);
  k_conv1 <<<db, 256, 0, stream>>>(S1, row_ptr, x, w1, root1, b1, h, N);
  // layer 2 (reuse S1 as S2; gather fully overwrites it)
  k_gather<<<gb, 256, 0, stream>>>(h, row_ptr, col_idx, S1, N);
  k_decode<<<db, 256, 0, stream>>>(S1, row_ptr, h, eps,
      w_mu, root_mu, b_mu, w_lv, root_lv, b_lv,
      fc1_w, fc1_b, fc2_w, fc2_b, (float*)d_out, N);
}